// Round 1
// baseline (23.986 us; speedup 1.0000x reference)
//
#include <hip/hip_runtime.h>

// HATS_65317862637845 — algebraic collapse:
// seg = dst*R + etype and the aggregated message is node_emb[dst], which is
// CONSTANT within each segment. Softmax weights sum to 1 per segment, so
// aggr[n,r] = node_emb[n] * [cnt(n,r) > 0]. The second-stage softmax over r
// (empty relations masked to -1e10 -> exp == 0 in f32) then gives
// new_emb[n] = node_emb[n] * [node n has >=1 incoming edge].
// Therefore: out[n] = node_emb[n] * (has_incoming_edge(n) ? 2.0f : 1.0f).

__global__ void hats_flag_dst(const int* __restrict__ dst,
                              int* __restrict__ flag, int E) {
    int i = blockIdx.x * blockDim.x + threadIdx.x;
    if (i < E) flag[dst[i]] = 1;   // write-write race writing identical value: benign
}

__global__ void hats_write_out(const float4* __restrict__ emb4,
                               const int* __restrict__ flag,
                               float4* __restrict__ out4, int n4) {
    int i = blockIdx.x * blockDim.x + threadIdx.x;
    if (i >= n4) return;
    // D = 128 floats per node -> 32 float4 per node -> node = i >> 5
    float4 v = emb4[i];
    float s = flag[i >> 5] ? 2.0f : 1.0f;
    v.x *= s; v.y *= s; v.z *= s; v.w *= s;
    out4[i] = v;
}

extern "C" void kernel_launch(void* const* d_in, const int* in_sizes, int n_in,
                              void* d_out, int out_size, void* d_ws, size_t ws_size,
                              hipStream_t stream) {
    // setup_inputs order:
    // 0 node_emb (N*D f32), 1 edge_embeddings, 2 basis_s, 3 coef_s, 4 b_s,
    // 5 basis_r, 6 coef_r, 7 b_r, 8 src, 9 dst, 10 etype
    const float* node_emb = (const float*)d_in[0];
    const int*   dst      = (const int*)d_in[9];
    const int E       = in_sizes[9];
    const int n_nodes = in_sizes[0] / 128;   // D = 128

    int* flag = (int*)d_ws;                  // n_nodes * 4 = 200 KB scratch

    // zero flags every call (graph includes this -> deterministic replays)
    hipMemsetAsync(flag, 0, (size_t)n_nodes * sizeof(int), stream);

    hats_flag_dst<<<(E + 255) / 256, 256, 0, stream>>>(dst, flag, E);

    const int n4 = out_size / 4;             // N*D/4 float4 elements
    hats_write_out<<<(n4 + 255) / 256, 256, 0, stream>>>(
        (const float4*)node_emb, flag, (float4*)d_out, n4);
}